// Round 9
// baseline (342.226 us; speedup 1.0000x reference)
//
#include <hip/hip_runtime.h>
#include <math.h>

typedef __attribute__((ext_vector_type(8))) __bf16 bf16x8;
typedef __attribute__((ext_vector_type(4))) float f32x4;
typedef __attribute__((ext_vector_type(16))) float f32x16;
typedef __attribute__((ext_vector_type(8))) unsigned short u16x8;
typedef __attribute__((ext_vector_type(8))) int i32x8;

#define GAS(p) ((const __attribute__((address_space(1))) void*)(p))
#define LAS(p) ((__attribute__((address_space(3))) void*)(p))

__device__ __forceinline__ unsigned short f2bf(float f) {
  union { float f; unsigned int u; } v; v.f = f;
  unsigned int r = (v.u + 0x7FFFu + ((v.u >> 16) & 1u)) >> 16;
  return (unsigned short)r;
}
__device__ __forceinline__ float bf2f(unsigned short b) {
  union { unsigned int u; float f; } v; v.u = ((unsigned int)b) << 16;
  return v.f;
}

// ---------------- fused f32 -> bf16 cast for z1,z2,w1,w2 ----------------
__global__ __launch_bounds__(256) void cast_all_kernel(
    const float* __restrict__ z1, const float* __restrict__ z2,
    const float* __restrict__ w1, const float* __restrict__ w2,
    unsigned short* __restrict__ z1b, unsigned short* __restrict__ z2b,
    unsigned short* __restrict__ w1b, unsigned short* __restrict__ w2b) {
  int b = blockIdx.x;
  const float* in; unsigned short* out; int base;
  if (b < 4096)       { in = z1; out = z1b; base = b; }
  else if (b < 8192)  { in = z2; out = z2b; base = b - 4096; }
  else if (b < 8448)  { in = w1; out = w1b; base = b - 8192; }
  else                { in = w2; out = w2b; base = b - 8448; }
  int i = (base * 256 + threadIdx.x) * 4;
  float4 v = *(const float4*)(in + i);
  ushort4 o;
  o.x = f2bf(v.x); o.y = f2bf(v.y); o.z = f2bf(v.z); o.w = f2bf(v.w);
  *(ushort4*)(out + i) = o;
}

// ---------------- core 128x128 NT bf16 tile, K=512 (projections) ----------------
__device__ __forceinline__ void gemm_tile_512(
    const unsigned short* __restrict__ A, const unsigned short* __restrict__ B,
    int m0, int n0, unsigned short* lA, unsigned short* lB, f32x4 acc[4][4]) {
  constexpr int K = 512;
  const int tid  = threadIdx.x;
  const int wave = tid >> 6;
  const int lane = tid & 63;
  const int quad = lane >> 4;
  const int l16  = lane & 15;
  const int wrow = (wave & 1) * 64;
  const int wcol = (wave >> 1) * 64;

  const f32x4 zero = {0.f, 0.f, 0.f, 0.f};
#pragma unroll
  for (int i = 0; i < 4; ++i)
#pragma unroll
    for (int j = 0; j < 4; ++j) acc[i][j] = zero;

  const int e0 = wave * 1024 + lane * 8;
  const int r0 = e0 >> 5, c0 = e0 & 31;
  const int e1 = e0 + 512;
  const int r1 = e1 >> 5, c1 = e1 & 31;

  const unsigned short* Ag0 = A + (size_t)(m0 + r0) * K + c0;
  const unsigned short* Ag1 = A + (size_t)(m0 + r1) * K + c1;
  const unsigned short* Bg0 = B + (size_t)(n0 + r0) * K + c0;
  const unsigned short* Bg1 = B + (size_t)(n0 + r1) * K + c1;

  for (int kt = 0; kt < K; kt += 32) {
    __syncthreads();
    __builtin_amdgcn_global_load_lds(GAS(Ag0 + kt), LAS(&lA[e0]), 16, 0, 0);
    __builtin_amdgcn_global_load_lds(GAS(Ag1 + kt), LAS(&lA[e1]), 16, 0, 0);
    __builtin_amdgcn_global_load_lds(GAS(Bg0 + kt), LAS(&lB[e0]), 16, 0, 0);
    __builtin_amdgcn_global_load_lds(GAS(Bg1 + kt), LAS(&lB[e1]), 16, 0, 0);
    __syncthreads();

    bf16x8 af[4], bfr[4];
#pragma unroll
    for (int i = 0; i < 4; ++i) {
      af[i]  = *(const bf16x8*)&lA[(wrow + i * 16 + l16) * 32 + quad * 8];
      bfr[i] = *(const bf16x8*)&lB[(wcol + i * 16 + l16) * 32 + quad * 8];
    }
#pragma unroll
    for (int mi = 0; mi < 4; ++mi)
#pragma unroll
      for (int ni = 0; ni < 4; ++ni)
        acc[mi][ni] = __builtin_amdgcn_mfma_f32_16x16x32_bf16(
            af[mi], bfr[ni], acc[mi][ni], 0, 0, 0);
  }
}

// ---------------- fused projection GEMM (2 inputs per launch) ----------------
template<int EPI>
__global__ __launch_bounds__(256)
void proj_kernel(const unsigned short* __restrict__ A1,
                 const unsigned short* __restrict__ A2,
                 const unsigned short* __restrict__ W,
                 const float* __restrict__ bias,
                 unsigned short* __restrict__ C1,
                 unsigned short* __restrict__ C2) {
  __shared__ unsigned short lA[128 * 32];
  __shared__ unsigned short lB[128 * 32];
  const int b = blockIdx.x;
  const int which = b >> 8;
  const int r = b & 255;
  const int n0 = (r & 3) * 128;
  const int m0 = (r >> 2) * 128;
  const unsigned short* A = which ? A2 : A1;
  unsigned short* C = which ? C2 : C1;

  f32x4 acc[4][4];
  gemm_tile_512(A, W, m0, n0, lA, lB, acc);

  const int lane = threadIdx.x & 63;
  const int wave = threadIdx.x >> 6;
  const int quad = lane >> 4;
  const int l16  = lane & 15;
  const int wrow = (wave & 1) * 64;
  const int wcol = (wave >> 1) * 64;

#pragma unroll
  for (int ni = 0; ni < 4; ++ni) {
    const int c = n0 + wcol + ni * 16 + l16;
    const float bv = bias[c];
#pragma unroll
    for (int mi = 0; mi < 4; ++mi) {
      const int rbase = m0 + wrow + mi * 16 + quad * 4;
#pragma unroll
      for (int rr = 0; rr < 4; ++rr) {
        float v = acc[mi][ni][rr] + bv;
        if constexpr (EPI == 0) v = (v > 0.f) ? v : expm1f(v);
        C[(size_t)(rbase + rr) * 512 + c] = f2bf(v);
      }
    }
  }
}

// ========== 32x32x64 MX-fp8 Gram: fragment-major LDS staging ==========
// q1/q2 in FRAGMENT-MAJOR 32-row-panel layout (R7-verified on HW):
//   panel p: 16384 B; within: kchunk kt(64 cols)*2048 + (klocal>>4)*512
//            + (row&31)*16 + (klocal&15)
// LDS staging is a VERBATIM byte-order copy of 4 A panels' + 4 B panels'
// K-range, so:
//   - global_load_lds reads contiguous 1 KB runs (perfect coalescing)
//   - fragment ds_read_b128 = wave-uniform base + lane*16: two dense 512-B
//     runs, uniform 8 words/bank -> ZERO bank conflicts by construction
// 32x32x64 keeps live fragments at 32 VGPRs (+64 AGPR acc) -> (256,3) with
// no spills (R6's failure mode).
__global__ __launch_bounds__(256, 3)
void gram_kernel(const unsigned char* __restrict__ q1,
                 const unsigned char* __restrict__ q2,
                 float* __restrict__ d11, float* __restrict__ d22,
                 float* __restrict__ d12r, float* __restrict__ d12c) {
  __shared__ unsigned char lA[4 * 4096];   // 4 panels x (2 k-steps x 2048 B)
  __shared__ unsigned char lB[4 * 4096];

  const int b = blockIdx.x;
  const unsigned char *A, *B;
  float *rsum, *csum;
  int m0, n0;
  if (b < 4160) {
    const bool first = (b < 2080);
    const unsigned char* h = first ? q1 : q2;
    float* d = first ? d11 : d22;
    int t = first ? b : b - 2080;
    int by = (int)((sqrtf(8.f * t + 1.f) - 1.f) * 0.5f);
    while ((by + 1) * (by + 2) / 2 <= t) ++by;
    while (by * (by + 1) / 2 > t) --by;
    int bx = t - by * (by + 1) / 2;
    A = h; B = h; m0 = by * 128; n0 = bx * 128;
    rsum = d; csum = (bx == by) ? nullptr : d;
  } else {
    int t = b - 4160;
    m0 = (t >> 6) * 128; n0 = (t & 63) * 128;
    A = q1; B = q2; rsum = d12r; csum = d12c;
  }

  const int tid  = threadIdx.x;
  const int wave = tid >> 6;
  const int lane = tid & 63;
  const int half = lane >> 5;      // k-half selector
  const int l31  = lane & 31;
  const int mbase = m0 + (wave & 1) * 64;
  const int nbase = n0 + (wave >> 1) * 64;

  // staging: wave w copies A panel w and B panel w (verbatim order)
  const unsigned char* Asrc = A + (size_t)((m0 >> 5) + wave) * 16384 + lane * 16;
  const unsigned char* Bsrc = B + (size_t)((n0 >> 5) + wave) * 16384 + lane * 16;
  unsigned char* Adst = lA + wave * 4096 + lane * 16;
  unsigned char* Bdst = lB + wave * 4096 + lane * 16;

  f32x16 acc[2][2];
#pragma unroll
  for (int i = 0; i < 2; ++i)
#pragma unroll
    for (int j = 0; j < 2; ++j)
#pragma unroll
      for (int r = 0; r < 16; ++r) acc[i][j][r] = 0.f;

  union frag { i32x8 v; int4 h[2]; };

  // LDS panel indices this wave computes with
  const int pa0 = (wave & 1) * 2;
  const int pb0 = (wave >> 1) * 2;
  const int lfo = half * 1024 + l31 * 16;   // fragment offset within panel-chunk

  for (int KT = 0; KT < 4; ++KT) {         // stage 128 cols (2 k-steps) per round
    __syncthreads();
#pragma unroll
    for (int t = 0; t < 4; ++t) {
      __builtin_amdgcn_global_load_lds(GAS(Asrc + KT * 4096 + t * 1024),
                                       LAS(Adst + t * 1024), 16, 0, 0);
      __builtin_amdgcn_global_load_lds(GAS(Bsrc + KT * 4096 + t * 1024),
                                       LAS(Bdst + t * 1024), 16, 0, 0);
    }
    __syncthreads();

#pragma unroll
    for (int ktl = 0; ktl < 2; ++ktl) {
      frag fa[2], fb[2];
#pragma unroll
      for (int i = 0; i < 2; ++i) {
        const int oa = (pa0 + i) * 4096 + ktl * 2048 + lfo;
        const int ob = (pb0 + i) * 4096 + ktl * 2048 + lfo;
        fa[i].h[0] = *(const int4*)&lA[oa];
        fa[i].h[1] = *(const int4*)&lA[oa + 512];
        fb[i].h[0] = *(const int4*)&lB[ob];
        fb[i].h[1] = *(const int4*)&lB[ob + 512];
      }
#pragma unroll
      for (int mi = 0; mi < 2; ++mi)
#pragma unroll
        for (int ni = 0; ni < 2; ++ni)
          acc[mi][ni] = __builtin_amdgcn_mfma_scale_f32_32x32x64_f8f6f4(
              fa[mi].v, fb[ni].v, acc[mi][ni],
              0, 0,                    // cbsz=e4m3, blgp=e4m3
              0, 0x7F7F7F7F,           // scale_a (E8M0 1.0)
              0, 0x7F7F7F7F);          // scale_b
    }
  }

  // epilogue: 32x32 C/D layout (m74/m101, R7-verified): col = lane&31,
  // row = (reg&3) + 8*(reg>>2) + 4*(lane>>5)
  float rs[2][16];
  float cs[2] = {0.f, 0.f};
#pragma unroll
  for (int mi = 0; mi < 2; ++mi)
#pragma unroll
    for (int r = 0; r < 16; ++r) rs[mi][r] = 0.f;
#pragma unroll
  for (int mi = 0; mi < 2; ++mi)
#pragma unroll
    for (int ni = 0; ni < 2; ++ni)
#pragma unroll
      for (int r = 0; r < 16; ++r) {
        float v = __expf(2.0f * acc[mi][ni][r]);
        rs[mi][r] += v;
        cs[ni] += v;
      }
#pragma unroll
  for (int mi = 0; mi < 2; ++mi) {
#pragma unroll
    for (int d = 1; d < 32; d <<= 1) {
#pragma unroll
      for (int r = 0; r < 16; ++r) rs[mi][r] += __shfl_xor(rs[mi][r], d, 64);
    }
    if (l31 == 0) {
#pragma unroll
      for (int r = 0; r < 16; ++r) {
        const int row = mbase + mi * 32 + (r & 3) + 8 * (r >> 2) + 4 * half;
        atomicAdd(&rsum[row], rs[mi][r]);
      }
    }
  }
  if (csum) {
#pragma unroll
    for (int ni = 0; ni < 2; ++ni) {
      float v = cs[ni] + __shfl_xor(cs[ni], 32, 64);
      if (half == 0) atomicAdd(&csum[nbase + ni * 32 + l31], v);
    }
  }
}

// ------- normalize -> fp8 in 32-row-panel FRAGMENT-MAJOR layout + diag dot -------
__global__ __launch_bounds__(256)
void norm_diag_kernel(const unsigned short* __restrict__ h1,
                      const unsigned short* __restrict__ h2,
                      unsigned char* __restrict__ q1,
                      unsigned char* __restrict__ q2,
                      float* __restrict__ cdiag) {
  const int wave = threadIdx.x >> 6, lane = threadIdx.x & 63;
  const int row = blockIdx.x * 4 + wave;
  const u16x8 u1 = *(const u16x8*)(h1 + (size_t)row * 512 + lane * 8);
  const u16x8 u2 = *(const u16x8*)(h2 + (size_t)row * 512 + lane * 8);
  float f1[8], f2[8], ss1 = 0.f, ss2 = 0.f;
#pragma unroll
  for (int j = 0; j < 8; ++j) {
    f1[j] = bf2f(u1[j]); ss1 += f1[j] * f1[j];
    f2[j] = bf2f(u2[j]); ss2 += f2[j] * f2[j];
  }
#pragma unroll
  for (int d = 1; d < 64; d <<= 1) {
    ss1 += __shfl_xor(ss1, d, 64);
    ss2 += __shfl_xor(ss2, d, 64);
  }
  const float inv1 = 1.0f / fmaxf(sqrtf(ss1), 1e-12f);
  const float inv2 = 1.0f / fmaxf(sqrtf(ss2), 1e-12f);
  float a[8], bb[8];
  float dot = 0.f;
#pragma unroll
  for (int j = 0; j < 8; ++j) {
    a[j] = f1[j] * inv1; bb[j] = f2[j] * inv2;
    dot += a[j] * bb[j];
  }
  int lo1 = __builtin_amdgcn_cvt_pk_fp8_f32(a[0], a[1], 0, false);
  lo1 = __builtin_amdgcn_cvt_pk_fp8_f32(a[2], a[3], lo1, true);
  int hi1 = __builtin_amdgcn_cvt_pk_fp8_f32(a[4], a[5], 0, false);
  hi1 = __builtin_amdgcn_cvt_pk_fp8_f32(a[6], a[7], hi1, true);
  int lo2 = __builtin_amdgcn_cvt_pk_fp8_f32(bb[0], bb[1], 0, false);
  lo2 = __builtin_amdgcn_cvt_pk_fp8_f32(bb[2], bb[3], lo2, true);
  int hi2 = __builtin_amdgcn_cvt_pk_fp8_f32(bb[4], bb[5], 0, false);
  hi2 = __builtin_amdgcn_cvt_pk_fp8_f32(bb[6], bb[7], hi2, true);

  // fragment-major dst: panel = row>>5, kt = c0>>6, sub = (c0>>4)&3
  const int c0 = lane * 8;
  const size_t dst = (size_t)(row >> 5) * 16384 + (c0 >> 6) * 2048
                   + ((c0 >> 4) & 3) * 512 + (row & 31) * 16 + (c0 & 15);
  *(int2*)(q1 + dst) = make_int2(lo1, hi1);
  *(int2*)(q2 + dst) = make_int2(lo2, hi2);
#pragma unroll
  for (int d = 1; d < 64; d <<= 1) dot += __shfl_xor(dot, d, 64);
  if (lane == 0) cdiag[row] = dot;
}

// ---------------- final scalar loss ----------------
__global__ __launch_bounds__(256)
void finalize_kernel(const float* __restrict__ d11, const float* __restrict__ d22,
                     const float* __restrict__ d12r, const float* __restrict__ d12c,
                     const float* __restrict__ cdiag, float* __restrict__ out) {
  const float e2 = 7.38905609893065f;
  float s = 0.f;
  for (int i = threadIdx.x; i < 8192; i += 256) {
    const float den1 = d11[i] + d12r[i] - e2;
    const float den2 = d22[i] + d12c[i] - e2;
    s += -2.0f * cdiag[i] + 0.5f * (logf(den1) + logf(den2));
  }
#pragma unroll
  for (int d = 1; d < 64; d <<= 1) s += __shfl_xor(s, d, 64);
  __shared__ float sm[4];
  if ((threadIdx.x & 63) == 0) sm[threadIdx.x >> 6] = s;
  __syncthreads();
  if (threadIdx.x == 0) out[0] = (sm[0] + sm[1] + sm[2] + sm[3]) * (1.0f / 8192.0f);
}

extern "C" void kernel_launch(void* const* d_in, const int* in_sizes, int n_in,
                              void* d_out, int out_size, void* d_ws, size_t ws_size,
                              hipStream_t stream) {
  const float* z1 = (const float*)d_in[0];
  const float* z2 = (const float*)d_in[1];
  const float* w1 = (const float*)d_in[2];
  const float* b1 = (const float*)d_in[3];
  const float* w2 = (const float*)d_in[4];
  const float* b2 = (const float*)d_in[5];
  float* out = (float*)d_out;

  const int N = 8192, D = 512;
  char* ws = (char*)d_ws;
  auto alloc = [&](size_t bytes) {
    char* p = ws; ws += (bytes + 255) & ~(size_t)255; return p;
  };
  unsigned short* z1b = (unsigned short*)alloc((size_t)N * D * 2);
  unsigned short* z2b = (unsigned short*)alloc((size_t)N * D * 2);
  unsigned short* g1  = (unsigned short*)alloc((size_t)N * D * 2);
  unsigned short* g2  = (unsigned short*)alloc((size_t)N * D * 2);
  unsigned short* w1b = (unsigned short*)alloc((size_t)D * D * 2);
  unsigned short* w2b = (unsigned short*)alloc((size_t)D * D * 2);
  float* sums  = (float*)alloc((size_t)4 * N * sizeof(float));
  float* cdiag = (float*)alloc((size_t)N * sizeof(float));
  float* d11 = sums, *d22 = sums + N, *d12r = sums + 2 * N, *d12c = sums + 3 * N;
  unsigned short* h1 = z1b;                 // stage-2 out aliases z buffers
  unsigned short* h2 = z2b;
  unsigned char* q1 = (unsigned char*)g1;   // fp8 aliases g (dead after proj2)
  unsigned char* q2 = (unsigned char*)g2;

  hipMemsetAsync(sums, 0, (size_t)4 * N * sizeof(float), stream);

  cast_all_kernel<<<dim3(8704), 256, 0, stream>>>(z1, z2, w1, w2, z1b, z2b, w1b, w2b);
  proj_kernel<0><<<dim3(512), 256, 0, stream>>>(z1b, z2b, w1b, b1, g1, g2);
  proj_kernel<1><<<dim3(512), 256, 0, stream>>>(g1, g2, w2b, b2, h1, h2);
  norm_diag_kernel<<<dim3(N / 4), 256, 0, stream>>>(h1, h2, q1, q2, cdiag);
  gram_kernel<<<dim3(8256), 256, 0, stream>>>(q1, q2, d11, d22, d12r, d12c);
  finalize_kernel<<<1, 256, 0, stream>>>(d11, d22, d12r, d12c, cdiag, out);
}

// Round 10
// 325.568 us; speedup vs baseline: 1.0512x; 1.0512x over previous
//
#include <hip/hip_runtime.h>
#include <math.h>

typedef __attribute__((ext_vector_type(8))) __bf16 bf16x8;
typedef __attribute__((ext_vector_type(4))) float f32x4;
typedef __attribute__((ext_vector_type(16))) float f32x16;
typedef __attribute__((ext_vector_type(8))) unsigned short u16x8;
typedef __attribute__((ext_vector_type(8))) int i32x8;

#define GAS(p) ((const __attribute__((address_space(1))) void*)(p))
#define LAS(p) ((__attribute__((address_space(3))) void*)(p))

__device__ __forceinline__ unsigned short f2bf(float f) {
  union { float f; unsigned int u; } v; v.f = f;
  unsigned int r = (v.u + 0x7FFFu + ((v.u >> 16) & 1u)) >> 16;
  return (unsigned short)r;
}
__device__ __forceinline__ float bf2f(unsigned short b) {
  union { unsigned int u; float f; } v; v.u = ((unsigned int)b) << 16;
  return v.f;
}

// ---------------- fused f32 -> bf16 cast for z1,z2,w1,w2 ----------------
__global__ __launch_bounds__(256) void cast_all_kernel(
    const float* __restrict__ z1, const float* __restrict__ z2,
    const float* __restrict__ w1, const float* __restrict__ w2,
    unsigned short* __restrict__ z1b, unsigned short* __restrict__ z2b,
    unsigned short* __restrict__ w1b, unsigned short* __restrict__ w2b) {
  int b = blockIdx.x;
  const float* in; unsigned short* out; int base;
  if (b < 4096)       { in = z1; out = z1b; base = b; }
  else if (b < 8192)  { in = z2; out = z2b; base = b - 4096; }
  else if (b < 8448)  { in = w1; out = w1b; base = b - 8192; }
  else                { in = w2; out = w2b; base = b - 8448; }
  int i = (base * 256 + threadIdx.x) * 4;
  float4 v = *(const float4*)(in + i);
  ushort4 o;
  o.x = f2bf(v.x); o.y = f2bf(v.y); o.z = f2bf(v.z); o.w = f2bf(v.w);
  *(ushort4*)(out + i) = o;
}

// ---------------- core 128x128 NT bf16 tile, K=512 (projections) ----------------
__device__ __forceinline__ void gemm_tile_512(
    const unsigned short* __restrict__ A, const unsigned short* __restrict__ B,
    int m0, int n0, unsigned short* lA, unsigned short* lB, f32x4 acc[4][4]) {
  constexpr int K = 512;
  const int tid  = threadIdx.x;
  const int wave = tid >> 6;
  const int lane = tid & 63;
  const int quad = lane >> 4;
  const int l16  = lane & 15;
  const int wrow = (wave & 1) * 64;
  const int wcol = (wave >> 1) * 64;

  const f32x4 zero = {0.f, 0.f, 0.f, 0.f};
#pragma unroll
  for (int i = 0; i < 4; ++i)
#pragma unroll
    for (int j = 0; j < 4; ++j) acc[i][j] = zero;

  const int e0 = wave * 1024 + lane * 8;
  const int r0 = e0 >> 5, c0 = e0 & 31;
  const int e1 = e0 + 512;
  const int r1 = e1 >> 5, c1 = e1 & 31;

  const unsigned short* Ag0 = A + (size_t)(m0 + r0) * K + c0;
  const unsigned short* Ag1 = A + (size_t)(m0 + r1) * K + c1;
  const unsigned short* Bg0 = B + (size_t)(n0 + r0) * K + c0;
  const unsigned short* Bg1 = B + (size_t)(n0 + r1) * K + c1;

  for (int kt = 0; kt < K; kt += 32) {
    __syncthreads();
    __builtin_amdgcn_global_load_lds(GAS(Ag0 + kt), LAS(&lA[e0]), 16, 0, 0);
    __builtin_amdgcn_global_load_lds(GAS(Ag1 + kt), LAS(&lA[e1]), 16, 0, 0);
    __builtin_amdgcn_global_load_lds(GAS(Bg0 + kt), LAS(&lB[e0]), 16, 0, 0);
    __builtin_amdgcn_global_load_lds(GAS(Bg1 + kt), LAS(&lB[e1]), 16, 0, 0);
    __syncthreads();

    bf16x8 af[4], bfr[4];
#pragma unroll
    for (int i = 0; i < 4; ++i) {
      af[i]  = *(const bf16x8*)&lA[(wrow + i * 16 + l16) * 32 + quad * 8];
      bfr[i] = *(const bf16x8*)&lB[(wcol + i * 16 + l16) * 32 + quad * 8];
    }
#pragma unroll
    for (int mi = 0; mi < 4; ++mi)
#pragma unroll
      for (int ni = 0; ni < 4; ++ni)
        acc[mi][ni] = __builtin_amdgcn_mfma_f32_16x16x32_bf16(
            af[mi], bfr[ni], acc[mi][ni], 0, 0, 0);
  }
}

// ---------------- fused projection GEMM (2 inputs per launch) ----------------
template<int EPI>
__global__ __launch_bounds__(256)
void proj_kernel(const unsigned short* __restrict__ A1,
                 const unsigned short* __restrict__ A2,
                 const unsigned short* __restrict__ W,
                 const float* __restrict__ bias,
                 unsigned short* __restrict__ C1,
                 unsigned short* __restrict__ C2) {
  __shared__ unsigned short lA[128 * 32];
  __shared__ unsigned short lB[128 * 32];
  const int b = blockIdx.x;
  const int which = b >> 8;
  const int r = b & 255;
  const int n0 = (r & 3) * 128;
  const int m0 = (r >> 2) * 128;
  const unsigned short* A = which ? A2 : A1;
  unsigned short* C = which ? C2 : C1;

  f32x4 acc[4][4];
  gemm_tile_512(A, W, m0, n0, lA, lB, acc);

  const int lane = threadIdx.x & 63;
  const int wave = threadIdx.x >> 6;
  const int quad = lane >> 4;
  const int l16  = lane & 15;
  const int wrow = (wave & 1) * 64;
  const int wcol = (wave >> 1) * 64;

#pragma unroll
  for (int ni = 0; ni < 4; ++ni) {
    const int c = n0 + wcol + ni * 16 + l16;
    const float bv = bias[c];
#pragma unroll
    for (int mi = 0; mi < 4; ++mi) {
      const int rbase = m0 + wrow + mi * 16 + quad * 4;
#pragma unroll
      for (int rr = 0; rr < 4; ++rr) {
        float v = acc[mi][ni][rr] + bv;
        if constexpr (EPI == 0) v = (v > 0.f) ? v : expm1f(v);
        C[(size_t)(rbase + rr) * 512 + c] = f2bf(v);
      }
    }
  }
}

// ========== 32x32x64 MX-fp8 Gram: fragment-major LDS staging ==========
// + XCD-RESIDUE BAND PARTITIONING (this round's change):
// dispatch round-robins blocks across 8 XCDs, so residue r = b&7 runs on one
// XCD and j = b>>3 is its local sequence. Each residue owns a disjoint
// 8-column tile band:
//   cross-gram: n-cols [8r, 8r+8), 512 tiles, row-major walk
//   tri1:       col band r       (484-64r tiles)
//   tri2:       col band 7-r     (36+64r tiles)   -> 520 tri tiles each
// Per-XCD steady working set = 8 B panels (512 KB, pinned) + ~12 streaming
// A panels ~= 1.25 MB << 4 MB L2 -> staging becomes L2-hit instead of the
// measured ~5 TB/s L3 path (R1/R2/R7/R9 all plateaued there).
__global__ __launch_bounds__(256, 3)
void gram_kernel(const unsigned char* __restrict__ q1,
                 const unsigned char* __restrict__ q2,
                 float* __restrict__ d11, float* __restrict__ d22,
                 float* __restrict__ d12r, float* __restrict__ d12c) {
  __shared__ unsigned char lA[4 * 4096];   // 4 panels x (2 k-steps x 2048 B)
  __shared__ unsigned char lB[4 * 4096];

  const int b = blockIdx.x;
  const int r = b & 7;        // XCD residue
  const int j = b >> 3;       // per-XCD sequence (0..1031)
  const unsigned char *A, *B;
  float *rsum, *csum;
  int m0, n0;
  const int n1 = 484 - 64 * r;            // tri1 band-r tile count
  if (j < 520) {
    // triangular segments (col bands)
    const bool first = (j < n1);
    const int k = first ? r : 7 - r;      // column band index
    int i = first ? j : j - n1;
    int by, c;
    if (i < 28) {                          // rows 8k..8k+6 (1..7 cols each)
      int t = 0;
      while ((t + 1) * (t + 2) / 2 <= i) ++t;
      by = 8 * k + t;
      c  = 8 * k + (i - t * (t + 1) / 2);
    } else {                               // rows 8k+7..63 (8 cols each)
      i -= 28;
      by = 8 * k + 7 + (i >> 3);
      c  = 8 * k + (i & 7);
    }
    const unsigned char* h = first ? q1 : q2;
    float* d = first ? d11 : d22;
    A = h; B = h; m0 = by * 128; n0 = c * 128;
    rsum = d; csum = (c == by) ? nullptr : d;
  } else {
    const int i = j - 520;                 // cross-gram band r, row-major
    m0 = (i >> 3) * 128;
    n0 = (r * 8 + (i & 7)) * 128;
    A = q1; B = q2; rsum = d12r; csum = d12c;
  }

  const int tid  = threadIdx.x;
  const int wave = tid >> 6;
  const int lane = tid & 63;
  const int half = lane >> 5;      // k-half selector
  const int l31  = lane & 31;
  const int mbase = m0 + (wave & 1) * 64;
  const int nbase = n0 + (wave >> 1) * 64;

  // staging: wave w copies A panel w and B panel w (verbatim order)
  const unsigned char* Asrc = A + (size_t)((m0 >> 5) + wave) * 16384 + lane * 16;
  const unsigned char* Bsrc = B + (size_t)((n0 >> 5) + wave) * 16384 + lane * 16;
  unsigned char* Adst = lA + wave * 4096 + lane * 16;
  unsigned char* Bdst = lB + wave * 4096 + lane * 16;

  f32x16 acc[2][2];
#pragma unroll
  for (int i = 0; i < 2; ++i)
#pragma unroll
    for (int jj = 0; jj < 2; ++jj)
#pragma unroll
      for (int rr = 0; rr < 16; ++rr) acc[i][jj][rr] = 0.f;

  union frag { i32x8 v; int4 h[2]; };

  // LDS panel indices this wave computes with
  const int pa0 = (wave & 1) * 2;
  const int pb0 = (wave >> 1) * 2;
  const int lfo = half * 1024 + l31 * 16;   // fragment offset within panel-chunk

  for (int KT = 0; KT < 4; ++KT) {         // stage 128 cols (2 k-steps) per round
    __syncthreads();
#pragma unroll
    for (int t = 0; t < 4; ++t) {
      __builtin_amdgcn_global_load_lds(GAS(Asrc + KT * 4096 + t * 1024),
                                       LAS(Adst + t * 1024), 16, 0, 0);
      __builtin_amdgcn_global_load_lds(GAS(Bsrc + KT * 4096 + t * 1024),
                                       LAS(Bdst + t * 1024), 16, 0, 0);
    }
    __syncthreads();

#pragma unroll
    for (int ktl = 0; ktl < 2; ++ktl) {
      frag fa[2], fb[2];
#pragma unroll
      for (int i = 0; i < 2; ++i) {
        const int oa = (pa0 + i) * 4096 + ktl * 2048 + lfo;
        const int ob = (pb0 + i) * 4096 + ktl * 2048 + lfo;
        fa[i].h[0] = *(const int4*)&lA[oa];
        fa[i].h[1] = *(const int4*)&lA[oa + 512];
        fb[i].h[0] = *(const int4*)&lB[ob];
        fb[i].h[1] = *(const int4*)&lB[ob + 512];
      }
#pragma unroll
      for (int mi = 0; mi < 2; ++mi)
#pragma unroll
        for (int ni = 0; ni < 2; ++ni)
          acc[mi][ni] = __builtin_amdgcn_mfma_scale_f32_32x32x64_f8f6f4(
              fa[mi].v, fb[ni].v, acc[mi][ni],
              0, 0,                    // cbsz=e4m3, blgp=e4m3
              0, 0x7F7F7F7F,           // scale_a (E8M0 1.0)
              0, 0x7F7F7F7F);          // scale_b
    }
  }

  // epilogue: 32x32 C/D layout (m74/m101, R7-verified): col = lane&31,
  // row = (reg&3) + 8*(reg>>2) + 4*(lane>>5)
  float rs[2][16];
  float cs[2] = {0.f, 0.f};
#pragma unroll
  for (int mi = 0; mi < 2; ++mi)
#pragma unroll
    for (int rr = 0; rr < 16; ++rr) rs[mi][rr] = 0.f;
#pragma unroll
  for (int mi = 0; mi < 2; ++mi)
#pragma unroll
    for (int ni = 0; ni < 2; ++ni)
#pragma unroll
      for (int rr = 0; rr < 16; ++rr) {
        float v = __expf(2.0f * acc[mi][ni][rr]);
        rs[mi][rr] += v;
        cs[ni] += v;
      }
#pragma unroll
  for (int mi = 0; mi < 2; ++mi) {
#pragma unroll
    for (int d = 1; d < 32; d <<= 1) {
#pragma unroll
      for (int rr = 0; rr < 16; ++rr) rs[mi][rr] += __shfl_xor(rs[mi][rr], d, 64);
    }
    if (l31 == 0) {
#pragma unroll
      for (int rr = 0; rr < 16; ++rr) {
        const int row = mbase + mi * 32 + (rr & 3) + 8 * (rr >> 2) + 4 * half;
        atomicAdd(&rsum[row], rs[mi][rr]);
      }
    }
  }
  if (csum) {
#pragma unroll
    for (int ni = 0; ni < 2; ++ni) {
      float v = cs[ni] + __shfl_xor(cs[ni], 32, 64);
      if (half == 0) atomicAdd(&csum[nbase + ni * 32 + l31], v);
    }
  }
}

// ------- normalize -> fp8 in 32-row-panel FRAGMENT-MAJOR layout + diag dot -------
__global__ __launch_bounds__(256)
void norm_diag_kernel(const unsigned short* __restrict__ h1,
                      const unsigned short* __restrict__ h2,
                      unsigned char* __restrict__ q1,
                      unsigned char* __restrict__ q2,
                      float* __restrict__ cdiag) {
  const int wave = threadIdx.x >> 6, lane = threadIdx.x & 63;
  const int row = blockIdx.x * 4 + wave;
  const u16x8 u1 = *(const u16x8*)(h1 + (size_t)row * 512 + lane * 8);
  const u16x8 u2 = *(const u16x8*)(h2 + (size_t)row * 512 + lane * 8);
  float f1[8], f2[8], ss1 = 0.f, ss2 = 0.f;
#pragma unroll
  for (int j = 0; j < 8; ++j) {
    f1[j] = bf2f(u1[j]); ss1 += f1[j] * f1[j];
    f2[j] = bf2f(u2[j]); ss2 += f2[j] * f2[j];
  }
#pragma unroll
  for (int d = 1; d < 64; d <<= 1) {
    ss1 += __shfl_xor(ss1, d, 64);
    ss2 += __shfl_xor(ss2, d, 64);
  }
  const float inv1 = 1.0f / fmaxf(sqrtf(ss1), 1e-12f);
  const float inv2 = 1.0f / fmaxf(sqrtf(ss2), 1e-12f);
  float a[8], bb[8];
  float dot = 0.f;
#pragma unroll
  for (int j = 0; j < 8; ++j) {
    a[j] = f1[j] * inv1; bb[j] = f2[j] * inv2;
    dot += a[j] * bb[j];
  }
  int lo1 = __builtin_amdgcn_cvt_pk_fp8_f32(a[0], a[1], 0, false);
  lo1 = __builtin_amdgcn_cvt_pk_fp8_f32(a[2], a[3], lo1, true);
  int hi1 = __builtin_amdgcn_cvt_pk_fp8_f32(a[4], a[5], 0, false);
  hi1 = __builtin_amdgcn_cvt_pk_fp8_f32(a[6], a[7], hi1, true);
  int lo2 = __builtin_amdgcn_cvt_pk_fp8_f32(bb[0], bb[1], 0, false);
  lo2 = __builtin_amdgcn_cvt_pk_fp8_f32(bb[2], bb[3], lo2, true);
  int hi2 = __builtin_amdgcn_cvt_pk_fp8_f32(bb[4], bb[5], 0, false);
  hi2 = __builtin_amdgcn_cvt_pk_fp8_f32(bb[6], bb[7], hi2, true);

  // fragment-major dst: panel = row>>5, kt = c0>>6, sub = (c0>>4)&3
  const int c0 = lane * 8;
  const size_t dst = (size_t)(row >> 5) * 16384 + (c0 >> 6) * 2048
                   + ((c0 >> 4) & 3) * 512 + (row & 31) * 16 + (c0 & 15);
  *(int2*)(q1 + dst) = make_int2(lo1, hi1);
  *(int2*)(q2 + dst) = make_int2(lo2, hi2);
#pragma unroll
  for (int d = 1; d < 64; d <<= 1) dot += __shfl_xor(dot, d, 64);
  if (lane == 0) cdiag[row] = dot;
}

// ---------------- final scalar loss ----------------
__global__ __launch_bounds__(256)
void finalize_kernel(const float* __restrict__ d11, const float* __restrict__ d22,
                     const float* __restrict__ d12r, const float* __restrict__ d12c,
                     const float* __restrict__ cdiag, float* __restrict__ out) {
  const float e2 = 7.38905609893065f;
  float s = 0.f;
  for (int i = threadIdx.x; i < 8192; i += 256) {
    const float den1 = d11[i] + d12r[i] - e2;
    const float den2 = d22[i] + d12c[i] - e2;
    s += -2.0f * cdiag[i] + 0.5f * (logf(den1) + logf(den2));
  }
#pragma unroll
  for (int d = 1; d < 64; d <<= 1) s += __shfl_xor(s, d, 64);
  __shared__ float sm[4];
  if ((threadIdx.x & 63) == 0) sm[threadIdx.x >> 6] = s;
  __syncthreads();
  if (threadIdx.x == 0) out[0] = (sm[0] + sm[1] + sm[2] + sm[3]) * (1.0f / 8192.0f);
}

extern "C" void kernel_launch(void* const* d_in, const int* in_sizes, int n_in,
                              void* d_out, int out_size, void* d_ws, size_t ws_size,
                              hipStream_t stream) {
  const float* z1 = (const float*)d_in[0];
  const float* z2 = (const float*)d_in[1];
  const float* w1 = (const float*)d_in[2];
  const float* b1 = (const float*)d_in[3];
  const float* w2 = (const float*)d_in[4];
  const float* b2 = (const float*)d_in[5];
  float* out = (float*)d_out;

  const int N = 8192, D = 512;
  char* ws = (char*)d_ws;
  auto alloc = [&](size_t bytes) {
    char* p = ws; ws += (bytes + 255) & ~(size_t)255; return p;
  };
  unsigned short* z1b = (unsigned short*)alloc((size_t)N * D * 2);
  unsigned short* z2b = (unsigned short*)alloc((size_t)N * D * 2);
  unsigned short* g1  = (unsigned short*)alloc((size_t)N * D * 2);
  unsigned short* g2  = (unsigned short*)alloc((size_t)N * D * 2);
  unsigned short* w1b = (unsigned short*)alloc((size_t)D * D * 2);
  unsigned short* w2b = (unsigned short*)alloc((size_t)D * D * 2);
  float* sums  = (float*)alloc((size_t)4 * N * sizeof(float));
  float* cdiag = (float*)alloc((size_t)N * sizeof(float));
  float* d11 = sums, *d22 = sums + N, *d12r = sums + 2 * N, *d12c = sums + 3 * N;
  unsigned short* h1 = z1b;                 // stage-2 out aliases z buffers
  unsigned short* h2 = z2b;
  unsigned char* q1 = (unsigned char*)g1;   // fp8 aliases g (dead after proj2)
  unsigned char* q2 = (unsigned char*)g2;

  hipMemsetAsync(sums, 0, (size_t)4 * N * sizeof(float), stream);

  cast_all_kernel<<<dim3(8704), 256, 0, stream>>>(z1, z2, w1, w2, z1b, z2b, w1b, w2b);
  proj_kernel<0><<<dim3(512), 256, 0, stream>>>(z1b, z2b, w1b, b1, g1, g2);
  proj_kernel<1><<<dim3(512), 256, 0, stream>>>(g1, g2, w2b, b2, h1, h2);
  norm_diag_kernel<<<dim3(N / 4), 256, 0, stream>>>(h1, h2, q1, q2, cdiag);
  gram_kernel<<<dim3(8256), 256, 0, stream>>>(q1, q2, d11, d22, d12r, d12c);
  finalize_kernel<<<1, 256, 0, stream>>>(d11, d22, d12r, d12c, cdiag, out);
}

// Round 11
// 240.612 us; speedup vs baseline: 1.4223x; 1.3531x over previous
//
#include <hip/hip_runtime.h>
#include <math.h>

typedef __attribute__((ext_vector_type(8))) __bf16 bf16x8;
typedef __attribute__((ext_vector_type(4))) float f32x4;
typedef __attribute__((ext_vector_type(16))) float f32x16;
typedef __attribute__((ext_vector_type(8))) unsigned short u16x8;
typedef __attribute__((ext_vector_type(8))) int i32x8;

#define GAS(p) ((const __attribute__((address_space(1))) void*)(p))
#define LAS(p) ((__attribute__((address_space(3))) void*)(p))

__device__ __forceinline__ unsigned short f2bf(float f) {
  union { float f; unsigned int u; } v; v.f = f;
  unsigned int r = (v.u + 0x7FFFu + ((v.u >> 16) & 1u)) >> 16;
  return (unsigned short)r;
}
__device__ __forceinline__ float bf2f(unsigned short b) {
  union { unsigned int u; float f; } v; v.u = ((unsigned int)b) << 16;
  return v.f;
}

// ---------------- fused f32 -> bf16 cast for z1,z2,w1,w2 ----------------
__global__ __launch_bounds__(256) void cast_all_kernel(
    const float* __restrict__ z1, const float* __restrict__ z2,
    const float* __restrict__ w1, const float* __restrict__ w2,
    unsigned short* __restrict__ z1b, unsigned short* __restrict__ z2b,
    unsigned short* __restrict__ w1b, unsigned short* __restrict__ w2b) {
  int b = blockIdx.x;
  const float* in; unsigned short* out; int base;
  if (b < 4096)       { in = z1; out = z1b; base = b; }
  else if (b < 8192)  { in = z2; out = z2b; base = b - 4096; }
  else if (b < 8448)  { in = w1; out = w1b; base = b - 8192; }
  else                { in = w2; out = w2b; base = b - 8448; }
  int i = (base * 256 + threadIdx.x) * 4;
  float4 v = *(const float4*)(in + i);
  ushort4 o;
  o.x = f2bf(v.x); o.y = f2bf(v.y); o.z = f2bf(v.z); o.w = f2bf(v.w);
  *(ushort4*)(out + i) = o;
}

// ---------------- core 128x128 NT bf16 tile, K=512 (projections) ----------------
__device__ __forceinline__ void gemm_tile_512(
    const unsigned short* __restrict__ A, const unsigned short* __restrict__ B,
    int m0, int n0, unsigned short* lA, unsigned short* lB, f32x4 acc[4][4]) {
  constexpr int K = 512;
  const int tid  = threadIdx.x;
  const int wave = tid >> 6;
  const int lane = tid & 63;
  const int quad = lane >> 4;
  const int l16  = lane & 15;
  const int wrow = (wave & 1) * 64;
  const int wcol = (wave >> 1) * 64;

  const f32x4 zero = {0.f, 0.f, 0.f, 0.f};
#pragma unroll
  for (int i = 0; i < 4; ++i)
#pragma unroll
    for (int j = 0; j < 4; ++j) acc[i][j] = zero;

  const int e0 = wave * 1024 + lane * 8;
  const int r0 = e0 >> 5, c0 = e0 & 31;
  const int e1 = e0 + 512;
  const int r1 = e1 >> 5, c1 = e1 & 31;

  const unsigned short* Ag0 = A + (size_t)(m0 + r0) * K + c0;
  const unsigned short* Ag1 = A + (size_t)(m0 + r1) * K + c1;
  const unsigned short* Bg0 = B + (size_t)(n0 + r0) * K + c0;
  const unsigned short* Bg1 = B + (size_t)(n0 + r1) * K + c1;

  for (int kt = 0; kt < K; kt += 32) {
    __syncthreads();
    __builtin_amdgcn_global_load_lds(GAS(Ag0 + kt), LAS(&lA[e0]), 16, 0, 0);
    __builtin_amdgcn_global_load_lds(GAS(Ag1 + kt), LAS(&lA[e1]), 16, 0, 0);
    __builtin_amdgcn_global_load_lds(GAS(Bg0 + kt), LAS(&lB[e0]), 16, 0, 0);
    __builtin_amdgcn_global_load_lds(GAS(Bg1 + kt), LAS(&lB[e1]), 16, 0, 0);
    __syncthreads();

    bf16x8 af[4], bfr[4];
#pragma unroll
    for (int i = 0; i < 4; ++i) {
      af[i]  = *(const bf16x8*)&lA[(wrow + i * 16 + l16) * 32 + quad * 8];
      bfr[i] = *(const bf16x8*)&lB[(wcol + i * 16 + l16) * 32 + quad * 8];
    }
#pragma unroll
    for (int mi = 0; mi < 4; ++mi)
#pragma unroll
      for (int ni = 0; ni < 4; ++ni)
        acc[mi][ni] = __builtin_amdgcn_mfma_f32_16x16x32_bf16(
            af[mi], bfr[ni], acc[mi][ni], 0, 0, 0);
  }
}

// ---------------- fused projection GEMM (2 inputs per launch) ----------------
template<int EPI>
__global__ __launch_bounds__(256)
void proj_kernel(const unsigned short* __restrict__ A1,
                 const unsigned short* __restrict__ A2,
                 const unsigned short* __restrict__ W,
                 const float* __restrict__ bias,
                 unsigned short* __restrict__ C1,
                 unsigned short* __restrict__ C2) {
  __shared__ unsigned short lA[128 * 32];
  __shared__ unsigned short lB[128 * 32];
  const int b = blockIdx.x;
  const int which = b >> 8;
  const int r = b & 255;
  const int n0 = (r & 3) * 128;
  const int m0 = (r >> 2) * 128;
  const unsigned short* A = which ? A2 : A1;
  unsigned short* C = which ? C2 : C1;

  f32x4 acc[4][4];
  gemm_tile_512(A, W, m0, n0, lA, lB, acc);

  const int lane = threadIdx.x & 63;
  const int wave = threadIdx.x >> 6;
  const int quad = lane >> 4;
  const int l16  = lane & 15;
  const int wrow = (wave & 1) * 64;
  const int wcol = (wave >> 1) * 64;

#pragma unroll
  for (int ni = 0; ni < 4; ++ni) {
    const int c = n0 + wcol + ni * 16 + l16;
    const float bv = bias[c];
#pragma unroll
    for (int mi = 0; mi < 4; ++mi) {
      const int rbase = m0 + wrow + mi * 16 + quad * 4;
#pragma unroll
      for (int rr = 0; rr < 4; ++rr) {
        float v = acc[mi][ni][rr] + bv;
        if constexpr (EPI == 0) v = (v > 0.f) ? v : expm1f(v);
        C[(size_t)(rbase + rr) * 512 + c] = f2bf(v);
      }
    }
  }
}

// ========== A-resident grouped 32x32x64 MX-fp8 Gram ==========
// Each block owns one A row-tile (128 rows, full K resident in LDS, 64 KB)
// and up to 4 consecutive B column-tiles; only B chunks (16 KB/KT) restage
// per tile. Staged volume drops 1.03 GB -> 0.65 GB (the empirical ~5.3 TB/s
// staging ceiling is the measured bottleneck across R1-R10). Cross-gram
// blocks are group-major so co-resident blocks share a hot 256 KB B group
// in local L2. Rowsums accumulate in registers across the group.
// Block map: [0,544) tri1 (q1,d11), [544,1088) tri2 (q2,d22),
//            [1088,2112) cross (q1 x q2 -> d12r/d12c), b=1088+g*64+row.
// Tri rows grouped in quads: rows 4q..4q+3 have q+1 groups each;
// cum before quad q = 2q(q+1).
__global__ __launch_bounds__(256, 2)
void gram_kernel(const unsigned char* __restrict__ q1,
                 const unsigned char* __restrict__ q2,
                 float* __restrict__ d11, float* __restrict__ d22,
                 float* __restrict__ d12r, float* __restrict__ d12c) {
  __shared__ unsigned char lA[65536];   // 4 panels x full K (fragment-major)
  __shared__ unsigned char lB[16384];   // 4 panels x one 128-col K-chunk

  const int b = blockIdx.x;
  const unsigned char *Abase, *Bbase;
  float *rptr, *cptr;
  int by, g, cnt;
  bool cross;
  if (b < 1088) {
    const bool first = (b < 544);
    int j = first ? b : b - 544;
    int q = (int)((sqrtf(2.f * j + 1.f) - 1.f) * 0.5f);
    while (2 * (q + 1) * (q + 2) <= j) ++q;
    while (2 * q * (q + 1) > j) --q;
    const int w = j - 2 * q * (q + 1);
    const int dr = w / (q + 1);
    g = w - dr * (q + 1);
    by = 4 * q + dr;
    const unsigned char* h = first ? q1 : q2;
    Abase = h; Bbase = h;
    rptr = first ? d11 : d22; cptr = rptr;
    cnt = min(4, by + 1 - g * 4);
    cross = false;
  } else {
    const int j = b - 1088;
    g = j >> 6; by = j & 63;
    Abase = q1; Bbase = q2;
    rptr = d12r; cptr = d12c;
    cnt = 4; cross = true;
  }

  const int tid  = threadIdx.x;
  const int wave = tid >> 6;
  const int lane = tid & 63;
  const int half = lane >> 5;
  const int l31  = lane & 31;
  const int pa0 = (wave & 1) * 2;
  const int pb0 = (wave >> 1) * 2;
  const int lfo = half * 1024 + l31 * 16;

  // staging pointers: wave w handles panel w
  const unsigned char* Asrc = Abase + (size_t)(by * 4 + wave) * 16384 + lane * 16;
  unsigned char* Adst = lA + wave * 16384 + lane * 16;
  unsigned char* Bdst = lB + wave * 4096 + lane * 16;

  union frag { i32x8 v; int4 h[2]; };

  float rs[2][16];
#pragma unroll
  for (int mi = 0; mi < 2; ++mi)
#pragma unroll
    for (int rr = 0; rr < 16; ++rr) rs[mi][rr] = 0.f;

  for (int t = 0; t < cnt; ++t) {
    const int ct = g * 4 + t;   // B column tile
    const unsigned char* Bsrc = Bbase + (size_t)(ct * 4 + wave) * 16384 + lane * 16;

    f32x16 acc[2][2];
#pragma unroll
    for (int i = 0; i < 2; ++i)
#pragma unroll
      for (int jj = 0; jj < 2; ++jj)
#pragma unroll
        for (int rr = 0; rr < 16; ++rr) acc[i][jj][rr] = 0.f;

    for (int KT = 0; KT < 4; ++KT) {
      __syncthreads();
      if (t == 0) {
#pragma unroll
        for (int i = 0; i < 4; ++i)
          __builtin_amdgcn_global_load_lds(GAS(Asrc + KT * 4096 + i * 1024),
                                           LAS(Adst + KT * 4096 + i * 1024), 16, 0, 0);
      }
#pragma unroll
      for (int i = 0; i < 4; ++i)
        __builtin_amdgcn_global_load_lds(GAS(Bsrc + KT * 4096 + i * 1024),
                                         LAS(Bdst + i * 1024), 16, 0, 0);
      __syncthreads();

#pragma unroll
      for (int ktl = 0; ktl < 2; ++ktl) {
        frag fa[2], fb[2];
#pragma unroll
        for (int i = 0; i < 2; ++i) {
          const int oa = (pa0 + i) * 16384 + KT * 4096 + ktl * 2048 + lfo;
          const int ob = (pb0 + i) * 4096 + ktl * 2048 + lfo;
          fa[i].h[0] = *(const int4*)&lA[oa];
          fa[i].h[1] = *(const int4*)&lA[oa + 512];
          fb[i].h[0] = *(const int4*)&lB[ob];
          fb[i].h[1] = *(const int4*)&lB[ob + 512];
        }
#pragma unroll
        for (int mi = 0; mi < 2; ++mi)
#pragma unroll
          for (int ni = 0; ni < 2; ++ni)
            acc[mi][ni] = __builtin_amdgcn_mfma_scale_f32_32x32x64_f8f6f4(
                fa[mi].v, fb[ni].v, acc[mi][ni],
                0, 0,                    // cbsz=e4m3, blgp=e4m3
                0, 0x7F7F7F7F,           // scale_a (E8M0 1.0)
                0, 0x7F7F7F7F);          // scale_b
      }
    }

    // per-tile epilogue: exp, accumulate rowsums in regs, colsum atomics
    float cs[2] = {0.f, 0.f};
#pragma unroll
    for (int mi = 0; mi < 2; ++mi)
#pragma unroll
      for (int ni = 0; ni < 2; ++ni)
#pragma unroll
        for (int rr = 0; rr < 16; ++rr) {
          float v = __expf(2.0f * acc[mi][ni][rr]);
          rs[mi][rr] += v;
          cs[ni] += v;
        }
    const bool diag = (!cross) && (ct == by);
    if (!diag) {
#pragma unroll
      for (int ni = 0; ni < 2; ++ni) {
        float v = cs[ni] + __shfl_xor(cs[ni], 32, 64);
        if (half == 0)
          atomicAdd(&cptr[ct * 128 + (wave >> 1) * 64 + ni * 32 + l31], v);
      }
    }
  }

  // rowsum: reduce over 32 column-lanes, one atomic set per block
#pragma unroll
  for (int mi = 0; mi < 2; ++mi) {
#pragma unroll
    for (int d = 1; d < 32; d <<= 1) {
#pragma unroll
      for (int rr = 0; rr < 16; ++rr) rs[mi][rr] += __shfl_xor(rs[mi][rr], d, 64);
    }
    if (l31 == 0) {
      const int mb = by * 128 + (wave & 1) * 64 + mi * 32;
#pragma unroll
      for (int rr = 0; rr < 16; ++rr) {
        const int row = mb + (rr & 3) + 8 * (rr >> 2) + 4 * half;
        atomicAdd(&rptr[row], rs[mi][rr]);
      }
    }
  }
}

// ------- normalize -> fp8 in 32-row-panel FRAGMENT-MAJOR layout + diag dot -------
__global__ __launch_bounds__(256)
void norm_diag_kernel(const unsigned short* __restrict__ h1,
                      const unsigned short* __restrict__ h2,
                      unsigned char* __restrict__ q1,
                      unsigned char* __restrict__ q2,
                      float* __restrict__ cdiag) {
  const int wave = threadIdx.x >> 6, lane = threadIdx.x & 63;
  const int row = blockIdx.x * 4 + wave;
  const u16x8 u1 = *(const u16x8*)(h1 + (size_t)row * 512 + lane * 8);
  const u16x8 u2 = *(const u16x8*)(h2 + (size_t)row * 512 + lane * 8);
  float f1[8], f2[8], ss1 = 0.f, ss2 = 0.f;
#pragma unroll
  for (int j = 0; j < 8; ++j) {
    f1[j] = bf2f(u1[j]); ss1 += f1[j] * f1[j];
    f2[j] = bf2f(u2[j]); ss2 += f2[j] * f2[j];
  }
#pragma unroll
  for (int d = 1; d < 64; d <<= 1) {
    ss1 += __shfl_xor(ss1, d, 64);
    ss2 += __shfl_xor(ss2, d, 64);
  }
  const float inv1 = 1.0f / fmaxf(sqrtf(ss1), 1e-12f);
  const float inv2 = 1.0f / fmaxf(sqrtf(ss2), 1e-12f);
  float a[8], bb[8];
  float dot = 0.f;
#pragma unroll
  for (int j = 0; j < 8; ++j) {
    a[j] = f1[j] * inv1; bb[j] = f2[j] * inv2;
    dot += a[j] * bb[j];
  }
  int lo1 = __builtin_amdgcn_cvt_pk_fp8_f32(a[0], a[1], 0, false);
  lo1 = __builtin_amdgcn_cvt_pk_fp8_f32(a[2], a[3], lo1, true);
  int hi1 = __builtin_amdgcn_cvt_pk_fp8_f32(a[4], a[5], 0, false);
  hi1 = __builtin_amdgcn_cvt_pk_fp8_f32(a[6], a[7], hi1, true);
  int lo2 = __builtin_amdgcn_cvt_pk_fp8_f32(bb[0], bb[1], 0, false);
  lo2 = __builtin_amdgcn_cvt_pk_fp8_f32(bb[2], bb[3], lo2, true);
  int hi2 = __builtin_amdgcn_cvt_pk_fp8_f32(bb[4], bb[5], 0, false);
  hi2 = __builtin_amdgcn_cvt_pk_fp8_f32(bb[6], bb[7], hi2, true);

  // fragment-major dst: panel = row>>5, kt = c0>>6, sub = (c0>>4)&3
  const int c0 = lane * 8;
  const size_t dst = (size_t)(row >> 5) * 16384 + (c0 >> 6) * 2048
                   + ((c0 >> 4) & 3) * 512 + (row & 31) * 16 + (c0 & 15);
  *(int2*)(q1 + dst) = make_int2(lo1, hi1);
  *(int2*)(q2 + dst) = make_int2(lo2, hi2);
#pragma unroll
  for (int d = 1; d < 64; d <<= 1) dot += __shfl_xor(dot, d, 64);
  if (lane == 0) cdiag[row] = dot;
}

// ---------------- final scalar loss ----------------
__global__ __launch_bounds__(256)
void finalize_kernel(const float* __restrict__ d11, const float* __restrict__ d22,
                     const float* __restrict__ d12r, const float* __restrict__ d12c,
                     const float* __restrict__ cdiag, float* __restrict__ out) {
  const float e2 = 7.38905609893065f;
  float s = 0.f;
  for (int i = threadIdx.x; i < 8192; i += 256) {
    const float den1 = d11[i] + d12r[i] - e2;
    const float den2 = d22[i] + d12c[i] - e2;
    s += -2.0f * cdiag[i] + 0.5f * (logf(den1) + logf(den2));
  }
#pragma unroll
  for (int d = 1; d < 64; d <<= 1) s += __shfl_xor(s, d, 64);
  __shared__ float sm[4];
  if ((threadIdx.x & 63) == 0) sm[threadIdx.x >> 6] = s;
  __syncthreads();
  if (threadIdx.x == 0) out[0] = (sm[0] + sm[1] + sm[2] + sm[3]) * (1.0f / 8192.0f);
}

extern "C" void kernel_launch(void* const* d_in, const int* in_sizes, int n_in,
                              void* d_out, int out_size, void* d_ws, size_t ws_size,
                              hipStream_t stream) {
  const float* z1 = (const float*)d_in[0];
  const float* z2 = (const float*)d_in[1];
  const float* w1 = (const float*)d_in[2];
  const float* b1 = (const float*)d_in[3];
  const float* w2 = (const float*)d_in[4];
  const float* b2 = (const float*)d_in[5];
  float* out = (float*)d_out;

  const int N = 8192, D = 512;
  char* ws = (char*)d_ws;
  auto alloc = [&](size_t bytes) {
    char* p = ws; ws += (bytes + 255) & ~(size_t)255; return p;
  };
  unsigned short* z1b = (unsigned short*)alloc((size_t)N * D * 2);
  unsigned short* z2b = (unsigned short*)alloc((size_t)N * D * 2);
  unsigned short* g1  = (unsigned short*)alloc((size_t)N * D * 2);
  unsigned short* g2  = (unsigned short*)alloc((size_t)N * D * 2);
  unsigned short* w1b = (unsigned short*)alloc((size_t)D * D * 2);
  unsigned short* w2b = (unsigned short*)alloc((size_t)D * D * 2);
  float* sums  = (float*)alloc((size_t)4 * N * sizeof(float));
  float* cdiag = (float*)alloc((size_t)N * sizeof(float));
  float* d11 = sums, *d22 = sums + N, *d12r = sums + 2 * N, *d12c = sums + 3 * N;
  unsigned short* h1 = z1b;                 // stage-2 out aliases z buffers
  unsigned short* h2 = z2b;
  unsigned char* q1 = (unsigned char*)g1;   // fp8 aliases g (dead after proj2)
  unsigned char* q2 = (unsigned char*)g2;

  hipMemsetAsync(sums, 0, (size_t)4 * N * sizeof(float), stream);

  cast_all_kernel<<<dim3(8704), 256, 0, stream>>>(z1, z2, w1, w2, z1b, z2b, w1b, w2b);
  proj_kernel<0><<<dim3(512), 256, 0, stream>>>(z1b, z2b, w1b, b1, g1, g2);
  proj_kernel<1><<<dim3(512), 256, 0, stream>>>(g1, g2, w2b, b2, h1, h2);
  norm_diag_kernel<<<dim3(N / 4), 256, 0, stream>>>(h1, h2, q1, q2, cdiag);
  gram_kernel<<<dim3(2112), 256, 0, stream>>>(q1, q2, d11, d22, d12r, d12c);
  finalize_kernel<<<1, 256, 0, stream>>>(d11, d22, d12r, d12c, cdiag, out);
}